// Round 1
// baseline (333.221 us; speedup 1.0000x reference)
//
#include <hip/hip_runtime.h>

#define NB 256
#define NS 197
#define ND 768
#define ND2 384
#define ND4 192
#define NPOOL 50
#define PROMPT_FLOATS 40320   // 42 * 960
#define PROMPT_V4 10080
#define TB 4                  // batches per block in MLP kernel

// ---------------- K1: mean over S + prompt broadcast ----------------
__global__ __launch_bounds__(768) void k_mean_bcast(
    const float* __restrict__ x,        // [B,S,D]
    const float* __restrict__ prompt,   // [1,42,960]
    const int* __restrict__ layer_num,
    float* __restrict__ xmean,          // ws [B,D]
    float* __restrict__ out_prompt)     // d_out section 3: [B, 40320]
{
    const int b = blockIdx.x;
    const int tid = threadIdx.x;
    const int lane = tid % 192;   // float4 index within a D-row (768/4)
    const int g = tid / 192;      // s-group 0..3

    const float4* __restrict__ xr =
        reinterpret_cast<const float4*>(x) + (size_t)b * (NS * (ND / 4));
    float4 acc = make_float4(0.f, 0.f, 0.f, 0.f);
    for (int s = g; s < NS; s += 4) {
        float4 v = xr[s * (ND / 4) + lane];
        acc.x += v.x; acc.y += v.y; acc.z += v.z; acc.w += v.w;
    }
    __shared__ float4 part[4][192];
    part[g][lane] = acc;
    __syncthreads();
    if (g == 0) {
        float4 p0 = part[0][lane], p1 = part[1][lane];
        float4 p2 = part[2][lane], p3 = part[3][lane];
        const float inv = 1.0f / (float)NS;
        float4 m;
        m.x = (p0.x + p1.x + p2.x + p3.x) * inv;
        m.y = (p0.y + p1.y + p2.y + p3.y) * inv;
        m.z = (p0.z + p1.z + p2.z + p3.z) * inv;
        m.w = (p0.w + p1.w + p2.w + p3.w) * inv;
        reinterpret_cast<float4*>(xmean + (size_t)b * ND)[lane] = m;
    }

    // prompt broadcast (independent of the mean)
    const float4* __restrict__ pv =
        reinterpret_cast<const float4*>(prompt + (size_t)layer_num[0] * PROMPT_FLOATS);
    float4* __restrict__ ov =
        reinterpret_cast<float4*>(out_prompt) + (size_t)b * PROMPT_V4;
    for (int i = tid; i < PROMPT_V4; i += 768) {
        ov[i] = pv[i];
    }
}

// ---------------- K2: MLP + l2norm + cosine sim ----------------
// Per-batch vectors (xmean, h, x_norm) are wave-uniform -> read with uniform
// global addresses so the compiler can emit scalar loads (SMEM path).
__global__ __launch_bounds__(256) void k_mlp(
    const float* __restrict__ xmean,  // ws [B, 768]
    const float* __restrict__ W1,     // [384, 768]
    const float* __restrict__ b1,     // [384]
    const float* __restrict__ W2,     // [192, 384]
    const float* __restrict__ b2,     // [192]
    const float* __restrict__ key,    // [50, 192]
    float* __restrict__ hbuf,         // ws [B, 384]
    float* __restrict__ sim,          // d_out [B, 50]
    float* __restrict__ xnorm)        // d_out+12800 [B, 192]
{
    const int tid = threadIdx.x;
    const int b0 = blockIdx.x * TB;

    // ---- GEMM1: h = relu(xmean @ W1^T + b1) ----
    const float4* __restrict__ xmv =
        reinterpret_cast<const float4*>(xmean + (size_t)b0 * ND);
    for (int i = tid; i < ND2; i += 256) {
        const float4* __restrict__ w =
            reinterpret_cast<const float4*>(W1 + (size_t)i * ND);
        float a0 = 0.f, a1 = 0.f, a2 = 0.f, a3 = 0.f;
        for (int k4 = 0; k4 < ND / 4; ++k4) {
            float4 wv = w[k4];
            float4 x0 = xmv[0 * (ND / 4) + k4];   // uniform
            float4 x1 = xmv[1 * (ND / 4) + k4];
            float4 x2 = xmv[2 * (ND / 4) + k4];
            float4 x3 = xmv[3 * (ND / 4) + k4];
            a0 += wv.x * x0.x + wv.y * x0.y + wv.z * x0.z + wv.w * x0.w;
            a1 += wv.x * x1.x + wv.y * x1.y + wv.z * x1.z + wv.w * x1.w;
            a2 += wv.x * x2.x + wv.y * x2.y + wv.z * x2.z + wv.w * x2.w;
            a3 += wv.x * x3.x + wv.y * x3.y + wv.z * x3.z + wv.w * x3.w;
        }
        float bias = b1[i];
        hbuf[(size_t)(b0 + 0) * ND2 + i] = fmaxf(a0 + bias, 0.f);
        hbuf[(size_t)(b0 + 1) * ND2 + i] = fmaxf(a1 + bias, 0.f);
        hbuf[(size_t)(b0 + 2) * ND2 + i] = fmaxf(a2 + bias, 0.f);
        hbuf[(size_t)(b0 + 3) * ND2 + i] = fmaxf(a3 + bias, 0.f);
    }
    __syncthreads();   // includes vmcnt drain; hbuf visible in L2

    // ---- GEMM2: feat = h @ W2^T + b2 ----
    __shared__ __align__(16) float fs[TB][ND4];
    if (tid < ND4) {
        const int j = tid;
        const float4* __restrict__ w =
            reinterpret_cast<const float4*>(W2 + (size_t)j * ND2);
        const float4* __restrict__ hv =
            reinterpret_cast<const float4*>(hbuf + (size_t)b0 * ND2);
        float a0 = 0.f, a1 = 0.f, a2 = 0.f, a3 = 0.f;
        for (int k4 = 0; k4 < ND2 / 4; ++k4) {
            float4 wv = w[k4];
            float4 h0 = hv[0 * (ND2 / 4) + k4];   // uniform
            float4 h1 = hv[1 * (ND2 / 4) + k4];
            float4 h2 = hv[2 * (ND2 / 4) + k4];
            float4 h3 = hv[3 * (ND2 / 4) + k4];
            a0 += wv.x * h0.x + wv.y * h0.y + wv.z * h0.z + wv.w * h0.w;
            a1 += wv.x * h1.x + wv.y * h1.y + wv.z * h1.z + wv.w * h1.w;
            a2 += wv.x * h2.x + wv.y * h2.y + wv.z * h2.z + wv.w * h2.w;
            a3 += wv.x * h3.x + wv.y * h3.y + wv.z * h3.z + wv.w * h3.w;
        }
        float bias = b2[j];
        fs[0][j] = a0 + bias;
        fs[1][j] = a1 + bias;
        fs[2][j] = a2 + bias;
        fs[3][j] = a3 + bias;
    }
    __syncthreads();

    // ---- per-batch squared-norm reduce: one wave per batch ----
    __shared__ float rs[TB];
    {
        const int w = tid / 64, l = tid % 64;
        if (w < TB) {
            float ss = 0.f;
            for (int j = l; j < ND4; j += 64) { float v = fs[w][j]; ss += v * v; }
            #pragma unroll
            for (int off = 32; off > 0; off >>= 1) ss += __shfl_down(ss, off);
            if (l == 0) rs[w] = rsqrtf(fmaxf(ss, 1e-12f));
        }
    }
    __syncthreads();

    // ---- normalize + write x_norm ----
    for (int idx = tid; idx < TB * ND4; idx += 256) {
        int b = idx / ND4, j = idx - b * ND4;
        float v = fs[b][j] * rs[b];
        xnorm[(size_t)(b0 + b) * ND4 + j] = v;
    }
    __syncthreads();   // xnorm stores drained -> visible for uniform loads

    // ---- similarity: 50 pool entries, read x_norm via uniform loads ----
    if (tid < NPOOL) {
        const int p = tid;
        const float4* __restrict__ kr =
            reinterpret_cast<const float4*>(key + (size_t)p * ND4);
        const float4* __restrict__ xn =
            reinterpret_cast<const float4*>(xnorm + (size_t)b0 * ND4);  // uniform
        float ss = 0.f;
        float d0 = 0.f, d1 = 0.f, d2 = 0.f, d3 = 0.f;
        for (int k4 = 0; k4 < ND4 / 4; ++k4) {
            float4 kv = kr[k4];
            ss += kv.x * kv.x + kv.y * kv.y + kv.z * kv.z + kv.w * kv.w;
            float4 x0 = xn[0 * (ND4 / 4) + k4];
            float4 x1 = xn[1 * (ND4 / 4) + k4];
            float4 x2 = xn[2 * (ND4 / 4) + k4];
            float4 x3 = xn[3 * (ND4 / 4) + k4];
            d0 += kv.x * x0.x + kv.y * x0.y + kv.z * x0.z + kv.w * x0.w;
            d1 += kv.x * x1.x + kv.y * x1.y + kv.z * x1.z + kv.w * x1.w;
            d2 += kv.x * x2.x + kv.y * x2.y + kv.z * x2.z + kv.w * x2.w;
            d3 += kv.x * x3.x + kv.y * x3.y + kv.z * x3.z + kv.w * x3.w;
        }
        float krs = rsqrtf(fmaxf(ss, 1e-12f));
        sim[(size_t)(b0 + 0) * NPOOL + p] = d0 * krs;
        sim[(size_t)(b0 + 1) * NPOOL + p] = d1 * krs;
        sim[(size_t)(b0 + 2) * NPOOL + p] = d2 * krs;
        sim[(size_t)(b0 + 3) * NPOOL + p] = d3 * krs;
    }
}

extern "C" void kernel_launch(void* const* d_in, const int* in_sizes, int n_in,
                              void* d_out, int out_size, void* d_ws, size_t ws_size,
                              hipStream_t stream) {
    const float* x        = (const float*)d_in[0];  // [256,197,768]
    const float* prompt   = (const float*)d_in[1];  // [1,42,960]
    const float* key      = (const float*)d_in[2];  // [50,192]
    const float* W1       = (const float*)d_in[3];  // [384,768]
    const float* b1       = (const float*)d_in[4];  // [384]
    const float* W2       = (const float*)d_in[5];  // [192,384]
    const float* b2       = (const float*)d_in[6];  // [192]
    const int*   layer_nm = (const int*)d_in[7];    // scalar

    float* out        = (float*)d_out;
    float* sim        = out;                 // [256,50]
    float* xnorm      = out + 12800;         // [256,192]
    float* out_prompt = out + 12800 + 49152; // [256,40320]

    float* xmean = (float*)d_ws;             // [256,768]
    float* hbuf  = xmean + NB * ND;          // [256,384]

    hipLaunchKernelGGL(k_mean_bcast, dim3(NB), dim3(768), 0, stream,
                       x, prompt, layer_nm, xmean, out_prompt);
    hipLaunchKernelGGL(k_mlp, dim3(NB / TB), dim3(256), 0, stream,
                       xmean, W1, b1, W2, b2, key, hbuf, sim, xnorm);
}

// Round 3
// 327.015 us; speedup vs baseline: 1.0190x; 1.0190x over previous
//
#include <hip/hip_runtime.h>

#define NB 256
#define NS 197
#define ND 768
#define ND2 384
#define ND4 192
#define NPOOL 50
#define PROMPT_FLOATS 40320   // 42 * 960
#define PROMPT_V4 10080
#define TB 2                  // batches per block in MLP kernel

// ---------------- K1: mean over S + prompt broadcast ----------------
__global__ __launch_bounds__(768) void k_mean_bcast(
    const float* __restrict__ x,        // [B,S,D]
    const float* __restrict__ prompt,   // [1,42,960]
    const int* __restrict__ layer_num,
    float* __restrict__ xmean,          // ws [B,D]
    float* __restrict__ out_prompt)     // d_out section 3: [B, 40320]
{
    const int b = blockIdx.x;
    const int tid = threadIdx.x;
    const int lane = tid % 192;   // float4 index within a D-row (768/4)
    const int g = tid / 192;      // s-group 0..3

    const float4* __restrict__ xr =
        reinterpret_cast<const float4*>(x) + (size_t)b * (NS * (ND / 4));
    float4 acc = make_float4(0.f, 0.f, 0.f, 0.f);
    for (int s = g; s < NS; s += 4) {
        float4 v = xr[s * (ND / 4) + lane];
        acc.x += v.x; acc.y += v.y; acc.z += v.z; acc.w += v.w;
    }
    __shared__ float4 part[4][192];
    part[g][lane] = acc;
    __syncthreads();
    if (g == 0) {
        float4 p0 = part[0][lane], p1 = part[1][lane];
        float4 p2 = part[2][lane], p3 = part[3][lane];
        const float inv = 1.0f / (float)NS;
        float4 m;
        m.x = (p0.x + p1.x + p2.x + p3.x) * inv;
        m.y = (p0.y + p1.y + p2.y + p3.y) * inv;
        m.z = (p0.z + p1.z + p2.z + p3.z) * inv;
        m.w = (p0.w + p1.w + p2.w + p3.w) * inv;
        reinterpret_cast<float4*>(xmean + (size_t)b * ND)[lane] = m;
    }

    // prompt broadcast (independent of the mean)
    const float4* __restrict__ pv =
        reinterpret_cast<const float4*>(prompt + (size_t)layer_num[0] * PROMPT_FLOATS);
    float4* __restrict__ ov =
        reinterpret_cast<float4*>(out_prompt) + (size_t)b * PROMPT_V4;
    for (int i = tid; i < PROMPT_V4; i += 768) {
        ov[i] = pv[i];
    }
}

// ---------------- K2: MLP + l2norm + cosine sim ----------------
// Coalesced W access: each 16-lane group owns one W-row and strides it in
// float4 (16 lanes x 16B = 256B contiguous per step); partial sums reduced
// with a 4-step __shfl_xor butterfly (masks 1/2/4/8 stay inside the group).
__global__ __launch_bounds__(512) void k_mlp(
    const float* __restrict__ xmean,  // ws [B, 768]
    const float* __restrict__ W1,     // [384, 768]
    const float* __restrict__ b1,     // [384]
    const float* __restrict__ W2,     // [192, 384]
    const float* __restrict__ b2,     // [192]
    const float* __restrict__ key,    // [50, 192]
    float* __restrict__ sim,          // d_out [B, 50]
    float* __restrict__ xnorm)        // d_out+12800 [B, 192]
{
    const int tid = threadIdx.x;
    const int g   = tid >> 4;   // group 0..31
    const int l   = tid & 15;   // lane within group
    const int b0  = blockIdx.x * TB;

    __shared__ __align__(16) float xm[TB][ND];    // 6 KB
    __shared__ __align__(16) float hs[TB][ND2];   // 3 KB
    __shared__ __align__(16) float fs[TB][ND4];   // 1.5 KB
    __shared__ float rs[TB];

    // stage xmean[TB][768] into LDS (coalesced float4)
    {
        const float4* __restrict__ src =
            reinterpret_cast<const float4*>(xmean + (size_t)b0 * ND);
        float4* dst = reinterpret_cast<float4*>(&xm[0][0]);
        for (int i = tid; i < TB * ND / 4; i += 512) dst[i] = src[i];
    }
    __syncthreads();

    // ---- GEMM1: h = relu(xmean @ W1^T + b1), row i per 16-lane group ----
    {
        const float4* __restrict__ x0v = reinterpret_cast<const float4*>(&xm[0][0]);
        const float4* __restrict__ x1v = reinterpret_cast<const float4*>(&xm[1][0]);
        for (int r = 0; r < ND2 / 32; ++r) {          // 12 rows per group
            const int i = g + 32 * r;
            const float4* __restrict__ w =
                reinterpret_cast<const float4*>(W1 + (size_t)i * ND);
            float a0 = 0.f, a1 = 0.f;
            #pragma unroll
            for (int s = 0; s < ND / 64; ++s) {       // 12 steps
                float4 wv = w[s * 16 + l];
                float4 x0 = x0v[s * 16 + l];
                float4 x1 = x1v[s * 16 + l];
                a0 += wv.x * x0.x + wv.y * x0.y + wv.z * x0.z + wv.w * x0.w;
                a1 += wv.x * x1.x + wv.y * x1.y + wv.z * x1.z + wv.w * x1.w;
            }
            #pragma unroll
            for (int m = 8; m; m >>= 1) {
                a0 += __shfl_xor(a0, m);
                a1 += __shfl_xor(a1, m);
            }
            if (l == 0) {
                float bias = b1[i];
                hs[0][i] = fmaxf(a0 + bias, 0.f);
                hs[1][i] = fmaxf(a1 + bias, 0.f);
            }
        }
    }
    __syncthreads();

    // ---- GEMM2: feat = h @ W2^T + b2 ----
    {
        const float4* __restrict__ h0v = reinterpret_cast<const float4*>(&hs[0][0]);
        const float4* __restrict__ h1v = reinterpret_cast<const float4*>(&hs[1][0]);
        for (int r = 0; r < ND4 / 32; ++r) {          // 6 rows per group
            const int j = g + 32 * r;
            const float4* __restrict__ w =
                reinterpret_cast<const float4*>(W2 + (size_t)j * ND2);
            float a0 = 0.f, a1 = 0.f;
            #pragma unroll
            for (int s = 0; s < ND2 / 64; ++s) {      // 6 steps
                float4 wv = w[s * 16 + l];
                float4 h0 = h0v[s * 16 + l];
                float4 h1 = h1v[s * 16 + l];
                a0 += wv.x * h0.x + wv.y * h0.y + wv.z * h0.z + wv.w * h0.w;
                a1 += wv.x * h1.x + wv.y * h1.y + wv.z * h1.z + wv.w * h1.w;
            }
            #pragma unroll
            for (int m = 8; m; m >>= 1) {
                a0 += __shfl_xor(a0, m);
                a1 += __shfl_xor(a1, m);
            }
            if (l == 0) {
                float bias = b2[j];
                fs[0][j] = a0 + bias;
                fs[1][j] = a1 + bias;
            }
        }
    }
    __syncthreads();

    // ---- per-batch squared-norm: wave w handles batch w ----
    if (tid < TB * 64) {
        const int w = tid >> 6, ll = tid & 63;
        float v0 = fs[w][ll], v1 = fs[w][ll + 64], v2 = fs[w][ll + 128];
        float ss = v0 * v0 + v1 * v1 + v2 * v2;
        #pragma unroll
        for (int m = 32; m; m >>= 1) ss += __shfl_xor(ss, m);
        if (ll == 0) rs[w] = rsqrtf(fmaxf(ss, 1e-12f));
    }
    __syncthreads();

    // ---- normalize in LDS + write x_norm ----
    for (int i = tid; i < TB * ND4; i += 512) {
        const int b = i / ND4, j = i - b * ND4;
        float v = fs[b][j] * rs[b];
        fs[b][j] = v;
        xnorm[(size_t)(b0 + b) * ND4 + j] = v;
    }
    __syncthreads();

    // ---- similarity: pool row per 16-lane group ----
    {
        const float4* __restrict__ x0v = reinterpret_cast<const float4*>(&fs[0][0]);
        const float4* __restrict__ x1v = reinterpret_cast<const float4*>(&fs[1][0]);
        for (int p = g; p < NPOOL; p += 32) {
            const float4* __restrict__ kr =
                reinterpret_cast<const float4*>(key + (size_t)p * ND4);
            float kk = 0.f, d0 = 0.f, d1 = 0.f;
            #pragma unroll
            for (int s = 0; s < ND4 / 64; ++s) {      // 3 steps
                float4 kv = kr[s * 16 + l];
                float4 x0 = x0v[s * 16 + l];
                float4 x1 = x1v[s * 16 + l];
                kk += kv.x * kv.x + kv.y * kv.y + kv.z * kv.z + kv.w * kv.w;
                d0 += kv.x * x0.x + kv.y * x0.y + kv.z * x0.z + kv.w * x0.w;
                d1 += kv.x * x1.x + kv.y * x1.y + kv.z * x1.z + kv.w * x1.w;
            }
            #pragma unroll
            for (int m = 8; m; m >>= 1) {
                kk += __shfl_xor(kk, m);
                d0 += __shfl_xor(d0, m);
                d1 += __shfl_xor(d1, m);
            }
            if (l == 0) {
                float krs = rsqrtf(fmaxf(kk, 1e-12f));
                sim[(size_t)(b0 + 0) * NPOOL + p] = d0 * krs;
                sim[(size_t)(b0 + 1) * NPOOL + p] = d1 * krs;
            }
        }
    }
}

extern "C" void kernel_launch(void* const* d_in, const int* in_sizes, int n_in,
                              void* d_out, int out_size, void* d_ws, size_t ws_size,
                              hipStream_t stream) {
    const float* x        = (const float*)d_in[0];  // [256,197,768]
    const float* prompt   = (const float*)d_in[1];  // [1,42,960]
    const float* key      = (const float*)d_in[2];  // [50,192]
    const float* W1       = (const float*)d_in[3];  // [384,768]
    const float* b1       = (const float*)d_in[4];  // [384]
    const float* W2       = (const float*)d_in[5];  // [192,384]
    const float* b2       = (const float*)d_in[6];  // [192]
    const int*   layer_nm = (const int*)d_in[7];    // scalar

    float* out        = (float*)d_out;
    float* sim        = out;                 // [256,50]
    float* xnorm      = out + 12800;         // [256,192]
    float* out_prompt = out + 12800 + 49152; // [256,40320]

    float* xmean = (float*)d_ws;             // [256,768]

    hipLaunchKernelGGL(k_mean_bcast, dim3(NB), dim3(768), 0, stream,
                       x, prompt, layer_nm, xmean, out_prompt);
    hipLaunchKernelGGL(k_mlp, dim3(NB / TB), dim3(512), 0, stream,
                       xmean, W1, b1, W2, b2, key, sim, xnorm);
}

// Round 7
// 266.138 us; speedup vs baseline: 1.2521x; 1.2287x over previous
//
#include <hip/hip_runtime.h>

#define NB 256
#define NS 197
#define ND 768
#define ND2 384
#define ND4 192
#define NPOOL 50
#define PROMPT_FLOATS 40320   // 42 * 960
#define PROMPT_V4 10080

// One block per batch: mean -> MLP -> l2norm -> sim -> prompt broadcast.
// 768 threads = 48 groups x 16 lanes. W-rows are read coalesced per group
// (16 lanes x float4 = 256B/step); K-reduction via __shfl_xor butterfly.
__global__ __launch_bounds__(768) void k_fused(
    const float* __restrict__ x,        // [B,S,D]
    const float* __restrict__ prompt,   // [1,42,960]
    const int* __restrict__ layer_num,
    const float* __restrict__ W1,       // [384,768]
    const float* __restrict__ b1,       // [384]
    const float* __restrict__ W2,       // [192,384]
    const float* __restrict__ b2,       // [192]
    const float* __restrict__ key,      // [50,192]
    float* __restrict__ sim,            // [B,50]
    float* __restrict__ xnorm,          // [B,192]
    float* __restrict__ out_prompt)     // [B,40320]
{
    const int b   = blockIdx.x;
    const int tid = threadIdx.x;
    const int g   = tid >> 4;   // group 0..47
    const int l   = tid & 15;   // lane in group

    __shared__ __align__(16) float4 part[4][192];  // 12 KB (mean partials)
    __shared__ __align__(16) float xm[ND];         // 3 KB
    __shared__ __align__(16) float hs[ND2];        // 1.5 KB
    __shared__ __align__(16) float fs[ND4];        // 0.75 KB
    __shared__ float rsv;

    // ---- mean over S: 4 s-groups x 192 float4 lanes ----
    {
        const int lane = tid % 192;
        const int sg   = tid / 192;
        const float4* __restrict__ xr =
            reinterpret_cast<const float4*>(x) + (size_t)b * (NS * (ND / 4));
        float4 acc = make_float4(0.f, 0.f, 0.f, 0.f);
        for (int s = sg; s < NS; s += 4) {
            float4 v = xr[s * (ND / 4) + lane];
            acc.x += v.x; acc.y += v.y; acc.z += v.z; acc.w += v.w;
        }
        part[sg][lane] = acc;
        __syncthreads();
        if (sg == 0) {
            float4 p0 = part[0][lane], p1 = part[1][lane];
            float4 p2 = part[2][lane], p3 = part[3][lane];
            const float inv = 1.0f / (float)NS;
            float4 m;
            m.x = (p0.x + p1.x + p2.x + p3.x) * inv;
            m.y = (p0.y + p1.y + p2.y + p3.y) * inv;
            m.z = (p0.z + p1.z + p2.z + p3.z) * inv;
            m.w = (p0.w + p1.w + p2.w + p3.w) * inv;
            reinterpret_cast<float4*>(xm)[lane] = m;
        }
    }
    __syncthreads();

    // ---- GEMM1: h = relu(xm @ W1^T + b1); 8 rows per group ----
    {
        const float4* __restrict__ xv = reinterpret_cast<const float4*>(xm);
        #pragma unroll
        for (int r = 0; r < ND2 / 48; ++r) {
            const int i = g + 48 * r;
            const float4* __restrict__ w =
                reinterpret_cast<const float4*>(W1 + (size_t)i * ND);
            float a = 0.f;
            #pragma unroll
            for (int s = 0; s < ND / 64; ++s) {      // 12 steps
                float4 wv = w[s * 16 + l];
                float4 xv4 = xv[s * 16 + l];
                a += wv.x * xv4.x + wv.y * xv4.y + wv.z * xv4.z + wv.w * xv4.w;
            }
            #pragma unroll
            for (int m = 8; m; m >>= 1) a += __shfl_xor(a, m);
            if (l == 0) hs[i] = fmaxf(a + b1[i], 0.f);
        }
    }
    __syncthreads();

    // ---- GEMM2: f = h @ W2^T + b2; 4 rows per group ----
    {
        const float4* __restrict__ hv = reinterpret_cast<const float4*>(hs);
        #pragma unroll
        for (int r = 0; r < ND4 / 48; ++r) {
            const int j = g + 48 * r;
            const float4* __restrict__ w =
                reinterpret_cast<const float4*>(W2 + (size_t)j * ND2);
            float a = 0.f;
            #pragma unroll
            for (int s = 0; s < ND2 / 64; ++s) {     // 6 steps
                float4 wv = w[s * 16 + l];
                float4 hv4 = hv[s * 16 + l];
                a += wv.x * hv4.x + wv.y * hv4.y + wv.z * hv4.z + wv.w * hv4.w;
            }
            #pragma unroll
            for (int m = 8; m; m >>= 1) a += __shfl_xor(a, m);
            if (l == 0) fs[j] = a + b2[j];
        }
    }
    __syncthreads();

    // ---- squared norm over 192 (first wave) ----
    if (tid < 64) {
        float v0 = fs[tid], v1 = fs[tid + 64], v2 = fs[tid + 128];
        float ss = v0 * v0 + v1 * v1 + v2 * v2;
        #pragma unroll
        for (int m = 32; m; m >>= 1) ss += __shfl_xor(ss, m);
        if (tid == 0) rsv = rsqrtf(fmaxf(ss, 1e-12f));
    }
    __syncthreads();

    // ---- normalize + write x_norm ----
    if (tid < ND4) {
        float v = fs[tid] * rsv;
        fs[tid] = v;
        xnorm[(size_t)b * ND4 + tid] = v;
    }
    __syncthreads();

    // ---- similarity: pool row per group (groups 0,1 take a 2nd row) ----
    {
        const float4* __restrict__ xv = reinterpret_cast<const float4*>(fs);
        for (int p = g; p < NPOOL; p += 48) {
            const float4* __restrict__ kr =
                reinterpret_cast<const float4*>(key + (size_t)p * ND4);
            float kk = 0.f, d = 0.f;
            #pragma unroll
            for (int s = 0; s < ND4 / 64; ++s) {     // 3 steps
                float4 kv = kr[s * 16 + l];
                float4 xv4 = xv[s * 16 + l];
                kk += kv.x * kv.x + kv.y * kv.y + kv.z * kv.z + kv.w * kv.w;
                d  += kv.x * xv4.x + kv.y * xv4.y + kv.z * xv4.z + kv.w * xv4.w;
            }
            #pragma unroll
            for (int m = 8; m; m >>= 1) {
                kk += __shfl_xor(kk, m);
                d  += __shfl_xor(d, m);
            }
            if (l == 0) sim[(size_t)b * NPOOL + p] = d * rsqrtf(fmaxf(kk, 1e-12f));
        }
    }

    // ---- prompt broadcast ----
    {
        const float4* __restrict__ pv =
            reinterpret_cast<const float4*>(prompt + (size_t)layer_num[0] * PROMPT_FLOATS);
        float4* __restrict__ ov =
            reinterpret_cast<float4*>(out_prompt) + (size_t)b * PROMPT_V4;
        for (int i = tid; i < PROMPT_V4; i += 768) {
            ov[i] = pv[i];
        }
    }
}

extern "C" void kernel_launch(void* const* d_in, const int* in_sizes, int n_in,
                              void* d_out, int out_size, void* d_ws, size_t ws_size,
                              hipStream_t stream) {
    const float* x        = (const float*)d_in[0];  // [256,197,768]
    const float* prompt   = (const float*)d_in[1];  // [1,42,960]
    const float* key      = (const float*)d_in[2];  // [50,192]
    const float* W1       = (const float*)d_in[3];  // [384,768]
    const float* b1       = (const float*)d_in[4];  // [384]
    const float* W2       = (const float*)d_in[5];  // [192,384]
    const float* b2       = (const float*)d_in[6];  // [192]
    const int*   layer_nm = (const int*)d_in[7];    // scalar

    float* out        = (float*)d_out;
    float* sim        = out;                 // [256,50]
    float* xnorm      = out + 12800;         // [256,192]
    float* out_prompt = out + 12800 + 49152; // [256,40320]

    hipLaunchKernelGGL(k_fused, dim3(NB), dim3(768), 0, stream,
                       x, prompt, layer_nm, W1, b1, W2, b2, key,
                       sim, xnorm, out_prompt);
}